// Round 8
// baseline (339.588 us; speedup 1.0000x reference)
//
#include <hip/hip_runtime.h>

#define D 64

// ===========================================================================
// disen_weight = softmax(disen_weight_att, axis=-1) @ relation_emb   [F, D]
// ===========================================================================
__global__ void disen_kernel(const float* __restrict__ att,   // [F, R]
                             const float* __restrict__ rel,   // [R, D]
                             float* __restrict__ disen,       // [F, D]
                             int nF, int nRel) {
    int d = threadIdx.x;
    if (d >= D) return;
    for (int f = 0; f < nF; ++f) {
        float m = -1e30f;
        for (int r = 0; r < nRel; ++r) m = fmaxf(m, att[f * nRel + r]);
        float sum = 0.0f, w = 0.0f;
        for (int r = 0; r < nRel; ++r) {
            float ex = __expf(att[f * nRel + r] - m);
            sum += ex;
            w   += ex * rel[r * D + d];
        }
        disen[f * D + d] = w / sum;
    }
}

// ===========================================================================
// FAST PATH: lock-free linked lists.
// Grouping = 1 divergent op per item (atomicExch on head) + 1 COALESCED
// next-store (node index == edge index). Divergent-op count halves vs the
// ticketed-bin scheme (R7's measured ~25G divergent-ops/s ceiling).
// Two chains per row (edge-index parity) give the walk 2x memory-level
// parallelism. No payload copies: the walk re-reads tail/type/col/val from
// the original arrays at wave-uniform addresses (broadcast, ~free).
// ===========================================================================
__global__ void fill_links(const int* __restrict__ eidx,   // [2, nE]; heads at [0,nE)
                           int nE,
                           const int* __restrict__ irows,  // [nnz]
                           int nnz,
                           int* __restrict__ head_e,       // [2*nEnt], init -1
                           int* __restrict__ next_e,       // [nE]
                           int* __restrict__ head_u,       // [2*nU], init -1
                           int* __restrict__ next_u,       // [nnz]
                           int quarter) {
    int i = blockIdx.x * blockDim.x + threadIdx.x;
    if (i >= quarter) return;   // R6 lesson: hard-bound; strided coverage below
    // segments [0,q),[q,2q),[2q,3q),[3q,4q) are disjoint and cover [0, max(nE,nnz))
#pragma unroll
    for (int k = 0; k < 4; ++k) {
        int e = i + k * quarter;
        if (e < nE) {
            int h = eidx[e];
            int p = atomicExch(&head_e[2 * h + (e & 1)], e);  // divergent (the 1 op)
            next_e[e] = p;                                     // coalesced
        }
        if (e < nnz) {
            int r = irows[e];
            int p = atomicExch(&head_u[2 * r + (e & 1)], e);
            next_u[e] = p;
        }
    }
}

// ===========================================================================
// Fused aggregation: wave per output row (entity rows first, then user rows).
// lane = dim. Walks the two chains interleaved; gathers are 256B coalesced.
// Every output element is written exactly once (no output pre-zero needed).
// ===========================================================================
__global__ void agg_all(const float* __restrict__ ent, const float* __restrict__ rel,
                        const int* __restrict__ eidx, const int* __restrict__ etype,
                        int nE,
                        const int* __restrict__ icols, const float* __restrict__ vals,
                        const int* __restrict__ head_e, const int* __restrict__ next_e,
                        const int* __restrict__ head_u, const int* __restrict__ next_u,
                        const float* __restrict__ uemb, const float* __restrict__ lat,
                        const float* __restrict__ disen,
                        float* __restrict__ eagg, float* __restrict__ uagg,
                        int nEnt, int nU) {
    int gid = blockIdx.x * blockDim.x + threadIdx.x;
    int row = gid >> 6;
    int d = gid & 63;

    if (row < nEnt) {
        int e0 = head_e[2 * row];
        int e1 = head_e[2 * row + 1];
        float a0 = 0.0f, a1 = 0.0f;
        int c = 0;
        while (e0 >= 0 || e1 >= 0) {
            if (e0 >= 0) {
                int nx   = next_e[e0];          // issue chain-advance early
                int tail = eidx[nE + e0];       // wave-uniform broadcast
                int ty   = etype[e0];
                a0 += ent[(size_t)tail * D + d] * rel[ty * D + d];
                ++c;
                e0 = nx;
            }
            if (e1 >= 0) {
                int nx   = next_e[e1];
                int tail = eidx[nE + e1];
                int ty   = etype[e1];
                a1 += ent[(size_t)tail * D + d] * rel[ty * D + d];
                ++c;
                e1 = nx;
            }
        }
        eagg[(size_t)row * D + d] = (a0 + a1) / fmaxf((float)c, 1.0f);
        return;
    }

    int u = row - nEnt;
    if (u >= nU) return;

    int e0 = head_u[2 * u];
    int e1 = head_u[2 * u + 1];
    float a0 = 0.0f, a1 = 0.0f;
    while (e0 >= 0 || e1 >= 0) {
        if (e0 >= 0) {
            int nx = next_u[e0];
            a0 += ent[(size_t)icols[e0] * D + d] * vals[e0];
            e0 = nx;
        }
        if (e1 >= 0) {
            int nx = next_u[e1];
            a1 += ent[(size_t)icols[e1] * D + d] * vals[e1];
            e1 = nx;
        }
    }
    float agg = a0 + a1;

    // score = softmax_f( dot(uemb[u], lat[f]) ) via full-wave shuffle reduce
    float e = uemb[(size_t)u * D + d];
    float s[4];
#pragma unroll
    for (int f = 0; f < 4; ++f) {
        float p = e * lat[f * D + d];
#pragma unroll
        for (int off = 32; off > 0; off >>= 1) p += __shfl_xor(p, off, 64);
        s[f] = p;
    }
    float m = fmaxf(fmaxf(s[0], s[1]), fmaxf(s[2], s[3]));
    float sum = 0.0f;
#pragma unroll
    for (int f = 0; f < 4; ++f) { s[f] = __expf(s[f] - m); sum += s[f]; }
    float inv = 1.0f / sum;
    float w = 0.0f;
#pragma unroll
    for (int f = 0; f < 4; ++f) w += (s[f] * inv) * disen[f * D + d];

    uagg[(size_t)u * D + d] = w * agg + agg;
}

// ===========================================================================
// FALLBACK: direct atomic scatter (round-3 proven path)
// ===========================================================================
__global__ void kg_scatter(const float* __restrict__ ent, const float* __restrict__ rel,
                           const int* __restrict__ eidx, const int* __restrict__ etype,
                           float* __restrict__ eagg, float* __restrict__ cnt, int nE) {
    int gid = blockIdx.x * blockDim.x + threadIdx.x;
    int e = gid >> 6;
    if (e >= nE) return;
    int d = gid & 63;
    int head = eidx[e];
    int tail = eidx[nE + e];
    int t = etype[e];
    float v = ent[tail * D + d] * rel[t * D + d];
    atomicAdd(&eagg[(size_t)head * D + d], v);
    if (d == 0) atomicAdd(&cnt[head], 1.0f);
}

__global__ void spmm_scatter(const float* __restrict__ ent, const float* __restrict__ vals,
                             const int* __restrict__ rows, const int* __restrict__ cols,
                             float* __restrict__ uagg, int nnz) {
    int gid = blockIdx.x * blockDim.x + threadIdx.x;
    int i = gid >> 6;
    if (i >= nnz) return;
    int d = gid & 63;
    float v = ent[cols[i] * D + d] * vals[i];
    atomicAdd(&uagg[(size_t)rows[i] * D + d], v);
}

__global__ void ent_norm(float* __restrict__ eagg, const float* __restrict__ cnt,
                         int total) {
    int gid = blockIdx.x * blockDim.x + threadIdx.x;
    if (gid >= total) return;
    float c = cnt[gid >> 6];
    eagg[gid] /= fmaxf(c, 1.0f);
}

__global__ void user_final(const float* __restrict__ uemb, const float* __restrict__ lat,
                           const float* __restrict__ disen, float* __restrict__ uagg,
                           int nU) {
    int gid = blockIdx.x * blockDim.x + threadIdx.x;
    int u = gid >> 6;
    if (u >= nU) return;
    int d = gid & 63;
    float e = uemb[(size_t)u * D + d];
    float s[4];
#pragma unroll
    for (int f = 0; f < 4; ++f) {
        float p = e * lat[f * D + d];
#pragma unroll
        for (int off = 32; off > 0; off >>= 1) p += __shfl_xor(p, off, 64);
        s[f] = p;
    }
    float m = fmaxf(fmaxf(s[0], s[1]), fmaxf(s[2], s[3]));
    float sum = 0.0f;
#pragma unroll
    for (int f = 0; f < 4; ++f) { s[f] = __expf(s[f] - m); sum += s[f]; }
    float inv = 1.0f / sum;
    float w = 0.0f;
#pragma unroll
    for (int f = 0; f < 4; ++f) w += (s[f] * inv) * disen[f * D + d];
    size_t o = (size_t)u * D + d;
    float base = uagg[o];
    uagg[o] = w * base + base;
}

// ===========================================================================
extern "C" void kernel_launch(void* const* d_in, const int* in_sizes, int n_in,
                              void* d_out, int out_size, void* d_ws, size_t ws_size,
                              hipStream_t stream) {
    const float* ent   = (const float*)d_in[0];
    const float* uemb  = (const float*)d_in[1];
    const float* lat   = (const float*)d_in[2];
    const float* rel   = (const float*)d_in[3];
    const float* att   = (const float*)d_in[4];
    const float* vals  = (const float*)d_in[5];
    const int*   eidx  = (const int*)d_in[6];
    const int*   etype = (const int*)d_in[7];
    const int*   irows = (const int*)d_in[8];
    const int*   icols = (const int*)d_in[9];

    int nEnt = in_sizes[0] / D;
    int nU   = in_sizes[1] / D;
    int nF   = in_sizes[2] / D;
    int nRel = in_sizes[3] / D;
    int nnz  = in_sizes[5];
    int nE   = in_sizes[6] / 2;

    float* eagg = (float*)d_out;
    float* uagg = (float*)d_out + (size_t)nEnt * D;

    // ---- workspace carve (256B-aligned) ----
    char* base = (char*)d_ws;
    size_t off = 0;
    auto carve = [&](size_t bytes) -> void* {
        void* r = base + off;
        off = (off + bytes + 255) & ~(size_t)255;
        return r;
    };
    float* disen  = (float*)carve((size_t)nF * D * 4);
    int*   head_e = (int*)carve((size_t)2 * nEnt * 4);
    int*   head_u = (int*)carve((size_t)2 * nU * 4);
    int*   next_e = (int*)carve((size_t)nE * 4);
    int*   next_u = (int*)carve((size_t)nnz * 4);
    size_t need = off;

    bool fast = (ws_size >= need) && (nF == 4);

    if (fast) {
        // heads -> -1 (0xFF bytes); single memset spans head_e..head_u (+pad)
        size_t head_span = (size_t)((char*)next_e - (char*)head_e);
        hipMemsetAsync(head_e, 0xFF, head_span, stream);

        disen_kernel<<<1, 64, 0, stream>>>(att, rel, disen, nF, nRel);

        int mx = (nE > nnz) ? nE : nnz;
        int quarter = (mx + 3) / 4;
        fill_links<<<(quarter + 255) / 256, 256, 0, stream>>>(
            eidx, nE, irows, nnz, head_e, next_e, head_u, next_u, quarter);

        long long rows = (long long)nEnt + nU;
        long long tot = rows * 64;
        agg_all<<<(int)((tot + 255) / 256), 256, 0, stream>>>(
            ent, rel, eidx, etype, nE, icols, vals,
            head_e, next_e, head_u, next_u,
            uemb, lat, disen, eagg, uagg, nEnt, nU);
        return;
    }

    // ---- fallback: direct atomics (round-3 proven path) ----
    {
        float* cnt = (float*)d_ws;
        size_t cnt_bytes = (((size_t)nEnt * sizeof(float)) + 255) & ~(size_t)255;
        float* disen3 = (float*)((char*)d_ws + cnt_bytes);

        hipMemsetAsync(d_out, 0, (size_t)out_size * sizeof(float), stream);
        hipMemsetAsync(cnt, 0, (size_t)nEnt * sizeof(float), stream);

        disen_kernel<<<1, 64, 0, stream>>>(att, rel, disen3, nF, nRel);
        {
            long long total = (long long)nE * 64;
            kg_scatter<<<(int)((total + 255) / 256), 256, 0, stream>>>(
                ent, rel, eidx, etype, eagg, cnt, nE);
        }
        {
            long long total = (long long)nnz * 64;
            spmm_scatter<<<(int)((total + 255) / 256), 256, 0, stream>>>(
                ent, vals, irows, icols, uagg, nnz);
        }
        {
            int total = nEnt * D;
            ent_norm<<<(total + 255) / 256, 256, 0, stream>>>(eagg, cnt, total);
        }
        {
            long long total = (long long)nU * 64;
            user_final<<<(int)((total + 255) / 256), 256, 0, stream>>>(
                uemb, lat, disen3, uagg, nU);
        }
    }
}